// Round 12
// baseline (93.209 us; speedup 1.0000x reference)
//
#include <hip/hip_runtime.h>

// Fused KernelWarehouse dynamic conv, round 9 (base: R10 82.2us, R11 85.0us):
//   logits = 1x1 conv -> softmax K=4 -> 3x3 convs -> mixture (dot2 f16 path).
// R11 falsified the vmcnt-drain theory. Per-iter accounting shows VALU+LDS+HBM
// demands ADD (2.8us/iter predicted, 2.56 measured): block barriers phase-lock
// the 4 waves, and 4 barrier domains/CU convoy the pipes.
// R12: BARRIER-FREE. 4096 one-wave blocks; each wave owns an 8x32 row-band and
// stages its own 10-row halo region into private LDS (1.8KB, single-buffered —
// wave-synchronous in-order DS pipe makes read(g) -> write(g+1) safe). All
// waits are per-wave counted s_waitcnt; 16 independent waves/CU interleave.
// XCD swizzle: fid = tw*512 + (b*32+br) -> all 8 horizontal neighbors of a
// band-row share fid mod 8 (same XCD -> halo 64B lines L2-hit).
// Kept: dot2/half2 channel pairs, packed weights in d_ws, 2-deep register
// prefetch, odd LDS stride 45 (<=2-way banks), f32 epilogue.

typedef _Float16 half2_t __attribute__((ext_vector_type(2)));
typedef unsigned int uint;

#define HH 256
#define WW 256
#define CH 64
#define PLANE (HH * WW)
#define NG 32                    // channel pairs (= groups)
#define BROWS 8                  // band rows per wave
#define RROWS 10                 // staged rows incl. halo
#define NC4 10                   // 4-dword units per row ([w0-4, w0+36))
#define LDSS 45                  // dword row stride (odd -> <=2-way read banks)
#define TU (RROWS * NC4)         // 100 units per group (unit = 4 px x 2 ch)
#define NS 2                     // units per lane (ceil 100/64)

// packed-weight table in d_ws:
//   uint wpk[4][32][9] : half2(w[k][2p][tap], w[k][2p+1][tap])  (1152)
//   uint apk[4][32]    : half2(attn_w[k][2p], attn_w[k][2p+1])  (128)
#define WPK_N 1152
#define APK_OFF 1152

__device__ __forceinline__ uint pkrtz(float a, float b) {
    return __builtin_bit_cast(uint, __builtin_amdgcn_cvt_pkrtz(a, b));
}

__device__ __forceinline__ float dot2(uint a, uint b, float c) {
#if __has_builtin(__builtin_amdgcn_fdot2)
    return __builtin_amdgcn_fdot2(__builtin_bit_cast(half2_t, a),
                                  __builtin_bit_cast(half2_t, b), c, false);
#else
    half2_t ha = __builtin_bit_cast(half2_t, a);
    half2_t hb = __builtin_bit_cast(half2_t, b);
    return c + (float)ha[0] * (float)hb[0] + (float)ha[1] * (float)hb[1];
#endif
}

__global__ void kwdc_pack(const float* __restrict__ weight,
                          const float* __restrict__ attn_w,
                          uint* __restrict__ wsu) {
    int e = blockIdx.x * 256 + threadIdx.x;
    if (e < WPK_N) {
        int k = e / 288, rem = e % 288, pair = rem / 9, tap = rem % 9;
        int c0 = 2 * pair;
        wsu[e] = pkrtz(weight[(k * CH + c0) * 9 + tap],
                       weight[(k * CH + c0 + 1) * 9 + tap]);
    } else if (e < WPK_N + 128) {
        int e2 = e - WPK_N;
        int k = e2 / 32, pair = e2 % 32;
        int c0 = 2 * pair;
        wsu[APK_OFF + e2] = pkrtz(attn_w[k * CH + c0], attn_w[k * CH + c0 + 1]);
    }
}

__global__ __launch_bounds__(64, 4) void kwdc_main(
    const float* __restrict__ x,       // [B,C,H,W] f32
    const uint*  __restrict__ wsu,     // packed weights (d_ws)
    const float* __restrict__ attn_b,  // [K] f32
    float* __restrict__ out)           // [B,1,H,W] f32
{
    __shared__ uint lds[RROWS * LDSS];   // 1.8 KB, wave-private (1-wave block)

    const int lane = threadIdx.x;

    // XCD swizzle: fid = tw*512 + (b*32 + br); row-neighbors (tw 0..7 at fixed
    // br,b) have fids 512 apart -> same fid mod 8 -> same XCD.
    const int fid = blockIdx.x;          // 0..4095
    const int tw  = fid >> 9;            // 0..7
    const int rem = fid & 511;
    const int b   = rem >> 5;            // 0..15
    const int br  = rem & 31;            // 0..31

    const int h0 = br * BROWS;
    const int w0 = tw * 32;

    const int r  = lane >> 3;    // 0..7 row in band
    const int cg = lane & 7;     // col group
    const int wb = cg * 4;       // col base (4-wide strip)

    const float* xb = x + (size_t)b * CH * PLANE;

    // ---- staging metadata (unit = 4 px of channels 2g,2g+1) ----
    int  s_gofs[NS];
    int  s_lofs[NS];
    bool s_val[NS];
    bool s_act[NS];
#pragma unroll
    for (int s = 0; s < NS; ++s) {
        int i = lane + s * 64;
        bool act = i < TU;
        int col4 = i % NC4;
        int row  = i / NC4;
        int gh  = h0 + row - 1;
        int gw0 = w0 - 4 + col4 * 4;     // 16B-aligned; fully in or fully out
        s_act[s]  = act;
        s_val[s]  = act && ((unsigned)gh < HH) && ((unsigned)gw0 < WW);
        s_gofs[s] = gh * WW + gw0;
        s_lofs[s] = row * LDSS + col4 * 4;
    }

    struct Unit { float4 a, b; };
    Unit stgA[NS], stgB[NS];             // 2-deep prefetch sets

    auto load_set = [&](int g, Unit* stg) {
#pragma unroll
        for (int s = 0; s < NS; ++s) {
            float4 va = {0.f, 0.f, 0.f, 0.f}, vb = va;
            if (s_val[s]) {
                const float* pa = xb + (size_t)(2 * g) * PLANE + s_gofs[s];
                va = *reinterpret_cast<const float4*>(pa);
                vb = *reinterpret_cast<const float4*>(pa + PLANE);
            }
            stg[s].a = va; stg[s].b = vb;
        }
    };

    auto store_set = [&](const Unit* stg) {
#pragma unroll
        for (int s = 0; s < NS; ++s) {
            if (s_act[s]) {
                uint* q = &lds[s_lofs[s]];
                q[0] = pkrtz(stg[s].a.x, stg[s].b.x);
                q[1] = pkrtz(stg[s].a.y, stg[s].b.y);
                q[2] = pkrtz(stg[s].a.z, stg[s].b.z);
                q[3] = pkrtz(stg[s].a.w, stg[s].b.w);
            }
        }
    };

    float conv[4][4];
    float logit[4][4];
#pragma unroll
    for (int k = 0; k < 4; ++k)
#pragma unroll
        for (int p = 0; p < 4; ++p) { conv[k][p] = 0.f; logit[k][p] = 0.f; }

    // ---- prologue: stage pair 0; prime 2-deep pipeline ----
    load_set(0, stgA);
    store_set(stgA);
    load_set(1, stgA);   // A holds g1
    load_set(2, stgB);   // B holds g2

    for (int g = 0; g < NG; ++g) {
        // ---- LDS reads for group g (before g+1 overwrites; in-order DS) ----
        const uint* tp = &lds[r * LDSS + wb + 3];
        uint rv[3][6];
#pragma unroll
        for (int i = 0; i < 3; ++i)
#pragma unroll
            for (int j = 0; j < 6; ++j)
                rv[i][j] = tp[i * LDSS + j];

        // ---- store g+1 (loaded 2 iters ago); refill set with g+3 ----
        if (g + 1 < NG) {
            Unit* setp = (g & 1) ? stgB : stgA;
            store_set(setp);
            if (g + 3 < NG) load_set(g + 3, setp);
        }

        // ---- packed weights for this pair (uniform -> s_load) ----
        uint w2[4][9];
        uint a2[4];
#pragma unroll
        for (int k = 0; k < 4; ++k) {
            const uint* wq = wsu + k * 288 + g * 9;
#pragma unroll
            for (int t = 0; t < 9; ++t) w2[k][t] = wq[t];
            a2[k] = wsu[APK_OFF + k * 32 + g];
        }

        // ---- compute both channels of the pair via dot2 ----
#pragma unroll
        for (int k = 0; k < 4; ++k) {
#pragma unroll
            for (int p = 0; p < 4; ++p) {
                float acc = conv[k][p];
                acc = dot2(rv[0][p],     w2[k][0], acc);
                acc = dot2(rv[0][p + 1], w2[k][1], acc);
                acc = dot2(rv[0][p + 2], w2[k][2], acc);
                acc = dot2(rv[1][p],     w2[k][3], acc);
                acc = dot2(rv[1][p + 1], w2[k][4], acc);
                acc = dot2(rv[1][p + 2], w2[k][5], acc);
                acc = dot2(rv[2][p],     w2[k][6], acc);
                acc = dot2(rv[2][p + 1], w2[k][7], acc);
                acc = dot2(rv[2][p + 2], w2[k][8], acc);
                conv[k][p] = acc;
                logit[k][p] = dot2(rv[1][p + 1], a2[k], logit[k][p]);
            }
        }
        // no barrier: LDS region is wave-private; compiler-counted lgkmcnt
        // orders read(g) -> write(g+1) -> read(g+1).
    }

    // ---- epilogue: softmax over K=4 + mixture (all f32) ----
    const float b0 = attn_b[0], b1 = attn_b[1], b2 = attn_b[2], b3 = attn_b[3];
    float4 o;
    float* op = &o.x;
#pragma unroll
    for (int p = 0; p < 4; ++p) {
        float l0 = logit[0][p] + b0;
        float l1 = logit[1][p] + b1;
        float l2 = logit[2][p] + b2;
        float l3 = logit[3][p] + b3;
        float m = fmaxf(fmaxf(l0, l1), fmaxf(l2, l3));
        float e0 = __expf(l0 - m), e1 = __expf(l1 - m);
        float e2 = __expf(l2 - m), e3 = __expf(l3 - m);
        float s = e0 + e1 + e2 + e3;
        float num = conv[0][p] * e0 + conv[1][p] * e1
                  + conv[2][p] * e2 + conv[3][p] * e3;
        op[p] = num / s;
    }
    size_t oidx = (size_t)b * PLANE + (size_t)(h0 + r) * WW + (w0 + wb);
    *reinterpret_cast<float4*>(out + oidx) = o;
}

extern "C" void kernel_launch(void* const* d_in, const int* in_sizes, int n_in,
                              void* d_out, int out_size, void* d_ws, size_t ws_size,
                              hipStream_t stream) {
    const float* x      = (const float*)d_in[0];
    const float* weight = (const float*)d_in[1];
    const float* attn_w = (const float*)d_in[2];
    const float* attn_b = (const float*)d_in[3];
    float* out = (float*)d_out;
    uint*  wsu = (uint*)d_ws;

    kwdc_pack<<<dim3(5), 256, 0, stream>>>(weight, attn_w, wsu);
    kwdc_main<<<dim3(4096), 64, 0, stream>>>(x, wsu, attn_b, out);
}

// Round 13
// 87.134 us; speedup vs baseline: 1.0697x; 1.0697x over previous
//
#include <hip/hip_runtime.h>

// Fused KernelWarehouse dynamic conv, round 10 (base: R10, 82.2us):
//   logits = 1x1 conv -> softmax K=4 -> 3x3 convs -> mixture (dot2 f16 path).
// R12 post-mortem: barriers exonerated (R11/R12 both null-to-worse). R10's
// accounting: HBM ~50us + LDS-pipe ~31us + VALU ~25us, partially overlapped.
// R13 attacks the LDS pipe only (everything else = R10 verbatim):
//  - LDSS=44, units stored via ONE ds_write_b128 (aligned; was 4 conflicted
//    b32 -- odd stride forced addr==3 mod 4).
//  - reads: per row one aligned ds_read_b128 (own 4 px) + halo via DPP
//    row_shr:1/row_shl:1 from neighbor lanes (VALU pipe!) + 8-lane masked
//    b32 fallback at strip edges (cg==0/7).
//  LDS cyc/wave-iter ~174 -> ~72; demand 31us -> ~15us.

typedef _Float16 half2_t __attribute__((ext_vector_type(2)));
typedef unsigned int uint;

#define HH 256
#define WW 256
#define CH 64
#define PLANE (HH * WW)
#define TILE 32
#define NG 32                    // channel pairs (= groups)
#define ROWS 34                  // tile rows incl. halo
#define NC4 10                   // 4-dword units per row ([w0-4, w0+36))
#define LDSS 44                  // dword row stride (mult of 4 -> aligned b128)
#define BUF_DW (ROWS * LDSS)     // 1496 dwords per buffer
#define TU (ROWS * NC4)          // 340 units per group (unit = 4 px x 2 ch)
#define NS 2                     // units per thread (ceil 340/256)

// packed-weight table in d_ws:
//   uint wpk[4][32][9] : half2(w[k][2p][tap], w[k][2p+1][tap])  (1152)
//   uint apk[4][32]    : half2(attn_w[k][2p], attn_w[k][2p+1])  (128)
#define WPK_N 1152
#define APK_OFF 1152

__device__ __forceinline__ uint pkrtz(float a, float b) {
    return __builtin_bit_cast(uint, __builtin_amdgcn_cvt_pkrtz(a, b));
}

__device__ __forceinline__ float dot2(uint a, uint b, float c) {
#if __has_builtin(__builtin_amdgcn_fdot2)
    return __builtin_amdgcn_fdot2(__builtin_bit_cast(half2_t, a),
                                  __builtin_bit_cast(half2_t, b), c, false);
#else
    half2_t ha = __builtin_bit_cast(half2_t, a);
    half2_t hb = __builtin_bit_cast(half2_t, b);
    return c + (float)ha[0] * (float)hb[0] + (float)ha[1] * (float)hb[1];
#endif
}

// lane L <- lane L-1 (16-lane DPP rows); invalid lanes replaced by caller
__device__ __forceinline__ uint dpp_shr1(uint v) {
#if __has_builtin(__builtin_amdgcn_update_dpp)
    return (uint)__builtin_amdgcn_update_dpp(0, (int)v, 0x111, 0xf, 0xf, true);
#else
    return (uint)__shfl_up((int)v, 1);
#endif
}
// lane L <- lane L+1
__device__ __forceinline__ uint dpp_shl1(uint v) {
#if __has_builtin(__builtin_amdgcn_update_dpp)
    return (uint)__builtin_amdgcn_update_dpp(0, (int)v, 0x101, 0xf, 0xf, true);
#else
    return (uint)__shfl_down((int)v, 1);
#endif
}

__global__ void kwdc_pack(const float* __restrict__ weight,
                          const float* __restrict__ attn_w,
                          uint* __restrict__ wsu) {
    int e = blockIdx.x * 256 + threadIdx.x;
    if (e < WPK_N) {
        int k = e / 288, rem = e % 288, pair = rem / 9, tap = rem % 9;
        int c0 = 2 * pair;
        wsu[e] = pkrtz(weight[(k * CH + c0) * 9 + tap],
                       weight[(k * CH + c0 + 1) * 9 + tap]);
    } else if (e < WPK_N + 128) {
        int e2 = e - WPK_N;
        int k = e2 / 32, pair = e2 % 32;
        int c0 = 2 * pair;
        wsu[APK_OFF + e2] = pkrtz(attn_w[k * CH + c0], attn_w[k * CH + c0 + 1]);
    }
}

__global__ __launch_bounds__(256, 4) void kwdc_main(
    const float* __restrict__ x,       // [B,C,H,W] f32
    const uint*  __restrict__ wsu,     // packed weights (d_ws)
    const float* __restrict__ attn_b,  // [K] f32
    float* __restrict__ out)           // [B,1,H,W] f32
{
    __shared__ __align__(16) uint lds[2][BUF_DW];   // 2 x 5.98 KB

    const int tid = threadIdx.x;

    // XCD-aware decode: the 8 tiles of an image row share fid mod 8 -> same XCD
    const int fid = blockIdx.x;        // 0..1023
    const int tw = (fid >> 3) & 7;
    const int th = fid & 7;
    const int b  = fid >> 6;

    const int r  = tid >> 3;     // 0..31 row in tile
    const int cg = tid & 7;      // col group
    const int wb = cg * 4;       // col base (4-wide strip)

    const int h0 = th * TILE;
    const int w0 = tw * TILE;

    const float* xb = x + (size_t)b * CH * PLANE;

    // ---- staging metadata (unit = 4 px of channels 2g,2g+1) ----
    // stored dword col = (gc - w0) + 8  -> unit base = 4*col4 + 4 (16B aligned)
    int  s_gofs[NS];
    int  s_lofs[NS];
    bool s_val[NS];
    bool s_act[NS];
#pragma unroll
    for (int s = 0; s < NS; ++s) {
        int i = tid + s * 256;
        bool act = i < TU;
        int col4 = i % NC4;
        int row  = i / NC4;
        int gh  = h0 + row - 1;
        int gw0 = w0 - 4 + col4 * 4;      // 16B-aligned; fully in or fully out
        s_act[s]  = act;
        s_val[s]  = act && ((unsigned)gh < HH) && ((unsigned)gw0 < WW);
        s_gofs[s] = gh * WW + gw0;
        s_lofs[s] = row * LDSS + col4 * 4 + 4;   // 16B aligned
    }

    struct Unit { float4 a, b; };
    Unit stgA[NS], stgB[NS];           // 2-deep prefetch sets

    auto load_set = [&](int g, Unit* stg) {
#pragma unroll
        for (int s = 0; s < NS; ++s) {
            float4 va = {0.f, 0.f, 0.f, 0.f}, vb = va;
            if (s_val[s]) {
                const float* pa = xb + (size_t)(2 * g) * PLANE + s_gofs[s];
                va = *reinterpret_cast<const float4*>(pa);
                vb = *reinterpret_cast<const float4*>(pa + PLANE);
            }
            stg[s].a = va; stg[s].b = vb;
        }
    };

    auto store_set = [&](const Unit* stg, int buf) {
#pragma unroll
        for (int s = 0; s < NS; ++s) {
            if (s_act[s]) {
                uint4 q;
                q.x = pkrtz(stg[s].a.x, stg[s].b.x);
                q.y = pkrtz(stg[s].a.y, stg[s].b.y);
                q.z = pkrtz(stg[s].a.z, stg[s].b.z);
                q.w = pkrtz(stg[s].a.w, stg[s].b.w);
                *reinterpret_cast<uint4*>(&lds[buf][s_lofs[s]]) = q;  // b128
            }
        }
    };

    float conv[4][4];
    float logit[4][4];
#pragma unroll
    for (int k = 0; k < 4; ++k)
#pragma unroll
        for (int p = 0; p < 4; ++p) { conv[k][p] = 0.f; logit[k][p] = 0.f; }

    // ---- prologue: stage pair 0; prime 2-deep pipeline ----
    load_set(0, stgA);
    store_set(stgA, 0);
    load_set(1, stgA);   // A holds g1 (stored at iter 0)
    load_set(2, stgB);   // B holds g2 (stored at iter 1)
    __syncthreads();     // buf0 ready

    for (int g = 0; g < NG; ++g) {
        // ---- LDS reads: per row 1 aligned b128 (own px) + DPP halo ----
        uint rv[3][6];
#pragma unroll
        for (int i = 0; i < 3; ++i) {
            const uint* rowbase = &lds[g & 1][(r + i) * LDSS];
            uint4 own = *reinterpret_cast<const uint4*>(rowbase + wb + 8);
            uint left  = dpp_shr1(own.w);     // lane-1's last px = col wb-1
            uint right = dpp_shl1(own.x);     // lane+1's first px = col wb+4
            if (cg == 0) left  = rowbase[wb + 7];    // strip edge: from LDS
            if (cg == 7) right = rowbase[wb + 12];
            rv[i][0] = left;
            rv[i][1] = own.x; rv[i][2] = own.y; rv[i][3] = own.z; rv[i][4] = own.w;
            rv[i][5] = right;
        }

        // ---- store set (holds g+1, loaded 2 iters ago); refill with g+3 ----
        if (g + 1 < NG) {
            Unit* setp = (g & 1) ? stgB : stgA;
            store_set(setp, (g + 1) & 1);
            if (g + 3 < NG) load_set(g + 3, setp);
        }

        // ---- packed weights for this pair (uniform -> s_load) ----
        uint w2[4][9];
        uint a2[4];
#pragma unroll
        for (int k = 0; k < 4; ++k) {
            const uint* wq = wsu + k * 288 + g * 9;
#pragma unroll
            for (int t = 0; t < 9; ++t) w2[k][t] = wq[t];
            a2[k] = wsu[APK_OFF + k * 32 + g];
        }

        // ---- compute both channels of the pair via dot2 ----
#pragma unroll
        for (int k = 0; k < 4; ++k) {
#pragma unroll
            for (int p = 0; p < 4; ++p) {
                float acc = conv[k][p];
                acc = dot2(rv[0][p],     w2[k][0], acc);
                acc = dot2(rv[0][p + 1], w2[k][1], acc);
                acc = dot2(rv[0][p + 2], w2[k][2], acc);
                acc = dot2(rv[1][p],     w2[k][3], acc);
                acc = dot2(rv[1][p + 1], w2[k][4], acc);
                acc = dot2(rv[1][p + 2], w2[k][5], acc);
                acc = dot2(rv[2][p],     w2[k][6], acc);
                acc = dot2(rv[2][p + 1], w2[k][7], acc);
                acc = dot2(rv[2][p + 2], w2[k][8], acc);
                conv[k][p] = acc;
                logit[k][p] = dot2(rv[1][p + 1], a2[k], logit[k][p]);
            }
        }
        // one barrier per group: buf[g&1] reads done before iter g+1 rewrites
        // it; buf[(g+1)&1] writes visible for iter g+1's compute
        __syncthreads();
    }

    // ---- epilogue: softmax over K=4 + mixture (all f32) ----
    const float b0 = attn_b[0], b1 = attn_b[1], b2 = attn_b[2], b3 = attn_b[3];
    float4 o;
    float* op = &o.x;
#pragma unroll
    for (int p = 0; p < 4; ++p) {
        float l0 = logit[0][p] + b0;
        float l1 = logit[1][p] + b1;
        float l2 = logit[2][p] + b2;
        float l3 = logit[3][p] + b3;
        float m = fmaxf(fmaxf(l0, l1), fmaxf(l2, l3));
        float e0 = __expf(l0 - m), e1 = __expf(l1 - m);
        float e2 = __expf(l2 - m), e3 = __expf(l3 - m);
        float s = e0 + e1 + e2 + e3;
        float num = conv[0][p] * e0 + conv[1][p] * e1
                  + conv[2][p] * e2 + conv[3][p] * e3;
        op[p] = num / s;
    }
    size_t oidx = (size_t)b * PLANE + (size_t)(h0 + r) * WW + (w0 + wb);
    *reinterpret_cast<float4*>(out + oidx) = o;
}

extern "C" void kernel_launch(void* const* d_in, const int* in_sizes, int n_in,
                              void* d_out, int out_size, void* d_ws, size_t ws_size,
                              hipStream_t stream) {
    const float* x      = (const float*)d_in[0];
    const float* weight = (const float*)d_in[1];
    const float* attn_w = (const float*)d_in[2];
    const float* attn_b = (const float*)d_in[3];
    float* out = (float*)d_out;
    uint*  wsu = (uint*)d_ws;

    kwdc_pack<<<dim3(5), 256, 0, stream>>>(weight, attn_w, wsu);
    kwdc_main<<<dim3(1024), 256, 0, stream>>>(x, wsu, attn_b, out);
}

// Round 14
// 84.567 us; speedup vs baseline: 1.1022x; 1.0304x over previous
//
#include <hip/hip_runtime.h>

// Fused KernelWarehouse dynamic conv, round 11 (base: R10, 82.2us):
//   logits = 1x1 conv -> softmax K=4 -> 3x3 convs -> mixture (dot2 f16 path).
// R11/R12/R13 falsified barrier & LDS-pipe theories (all wash/worse). R10 is
// memory-dominated: staged bytes = 1.328x useful (40/32 cols x 34/32 rows).
// R14: 32-row x 64-col tiles -> staging overhead 1.195x (72/64 x 34/32), a
// guaranteed -10% fetch independent of L2 halo-sharing. 512-thr blocks,
// grid 512 = 2 blocks/CU -> 16 waves/CU (R10's occupancy). LDSS=73 (odd;
// read banks (9r+4cg+j)%32 = exact 2-way = free). Rest = R10 verbatim:
// CPB=2 LDS double-buffer, 2-deep reg prefetch, 1 barrier/group, dot2
// channel pairs, packed weights in d_ws (s_loads hoisted before store).

typedef _Float16 half2_t __attribute__((ext_vector_type(2)));
typedef unsigned int uint;

#define HH 256
#define WW 256
#define CH 64
#define PLANE (HH * WW)
#define NT 512                   // threads per block
#define TR 32                    // tile rows
#define TC 64                    // tile cols
#define NG 32                    // channel pairs (= groups)
#define ROWS 34                  // tile rows incl. halo
#define NC4 18                   // 4-dword units per row ([w0-4, w0+68))
#define LDSS 73                  // dword row stride (odd -> <=2-way read banks)
#define BUF_DW (ROWS * LDSS)     // 2482 dwords per buffer (9.9 KB)
#define TU (ROWS * NC4)          // 612 units per group (unit = 4 px x 2 ch)
#define NS 2                     // units per thread (ceil 612/512)

// packed-weight table in d_ws:
//   uint wpk[4][32][9] : half2(w[k][2p][tap], w[k][2p+1][tap])  (1152)
//   uint apk[4][32]    : half2(attn_w[k][2p], attn_w[k][2p+1])  (128)
#define WPK_N 1152
#define APK_OFF 1152

__device__ __forceinline__ uint pkrtz(float a, float b) {
    return __builtin_bit_cast(uint, __builtin_amdgcn_cvt_pkrtz(a, b));
}

__device__ __forceinline__ float dot2(uint a, uint b, float c) {
#if __has_builtin(__builtin_amdgcn_fdot2)
    return __builtin_amdgcn_fdot2(__builtin_bit_cast(half2_t, a),
                                  __builtin_bit_cast(half2_t, b), c, false);
#else
    half2_t ha = __builtin_bit_cast(half2_t, a);
    half2_t hb = __builtin_bit_cast(half2_t, b);
    return c + (float)ha[0] * (float)hb[0] + (float)ha[1] * (float)hb[1];
#endif
}

__global__ void kwdc_pack(const float* __restrict__ weight,
                          const float* __restrict__ attn_w,
                          uint* __restrict__ wsu) {
    int e = blockIdx.x * 256 + threadIdx.x;
    if (e < WPK_N) {
        int k = e / 288, rem = e % 288, pair = rem / 9, tap = rem % 9;
        int c0 = 2 * pair;
        wsu[e] = pkrtz(weight[(k * CH + c0) * 9 + tap],
                       weight[(k * CH + c0 + 1) * 9 + tap]);
    } else if (e < WPK_N + 128) {
        int e2 = e - WPK_N;
        int k = e2 / 32, pair = e2 % 32;
        int c0 = 2 * pair;
        wsu[APK_OFF + e2] = pkrtz(attn_w[k * CH + c0], attn_w[k * CH + c0 + 1]);
    }
}

__global__ __launch_bounds__(NT, 4) void kwdc_main(
    const float* __restrict__ x,       // [B,C,H,W] f32
    const uint*  __restrict__ wsu,     // packed weights (d_ws)
    const float* __restrict__ attn_b,  // [K] f32
    float* __restrict__ out)           // [B,1,H,W] f32
{
    __shared__ uint lds[2][BUF_DW];    // 2 x 9.9 KB

    const int tid = threadIdx.x;

    // XCD-aware decode: the 4 row-mate tiles (tw 0..3) share fid mod 8
    const int fid = blockIdx.x;        // 0..511
    const int tw = (fid >> 3) & 3;     // 0..3
    const int th = fid & 7;            // 0..7
    const int b  = fid >> 5;           // 0..15

    const int r  = tid >> 4;     // 0..31 row in tile
    const int cg = tid & 15;     // col group
    const int wb = cg * 4;       // col base (4-wide strip)

    const int h0 = th * TR;
    const int w0 = tw * TC;

    const float* xb = x + (size_t)b * CH * PLANE;

    // ---- staging metadata (unit = 4 px of channels 2g,2g+1) ----
    int  s_gofs[NS];
    int  s_lofs[NS];
    bool s_val[NS];
    bool s_act[NS];
#pragma unroll
    for (int s = 0; s < NS; ++s) {
        int i = tid + s * NT;
        bool act = i < TU;
        int col4 = i % NC4;
        int row  = i / NC4;
        int gh  = h0 + row - 1;
        int gw0 = w0 - 4 + col4 * 4;      // 16B-aligned; fully in or fully out
        s_act[s]  = act;
        s_val[s]  = act && ((unsigned)gh < HH) && ((unsigned)gw0 < WW);
        s_gofs[s] = gh * WW + gw0;
        s_lofs[s] = row * LDSS + col4 * 4;
    }

    struct Unit { float4 a, b; };
    Unit stgA[NS], stgB[NS];           // 2-deep prefetch sets

    auto load_set = [&](int g, Unit* stg) {
#pragma unroll
        for (int s = 0; s < NS; ++s) {
            float4 va = {0.f, 0.f, 0.f, 0.f}, vb = va;
            if (s_val[s]) {
                const float* pa = xb + (size_t)(2 * g) * PLANE + s_gofs[s];
                va = *reinterpret_cast<const float4*>(pa);
                vb = *reinterpret_cast<const float4*>(pa + PLANE);
            }
            stg[s].a = va; stg[s].b = vb;
        }
    };

    auto store_set = [&](const Unit* stg, int buf) {
#pragma unroll
        for (int s = 0; s < NS; ++s) {
            if (s_act[s]) {
                uint* q = &lds[buf][s_lofs[s]];
                q[0] = pkrtz(stg[s].a.x, stg[s].b.x);
                q[1] = pkrtz(stg[s].a.y, stg[s].b.y);
                q[2] = pkrtz(stg[s].a.z, stg[s].b.z);
                q[3] = pkrtz(stg[s].a.w, stg[s].b.w);
            }
        }
    };

    float conv[4][4];
    float logit[4][4];
#pragma unroll
    for (int k = 0; k < 4; ++k)
#pragma unroll
        for (int p = 0; p < 4; ++p) { conv[k][p] = 0.f; logit[k][p] = 0.f; }

    // ---- prologue: stage pair 0; prime 2-deep pipeline ----
    load_set(0, stgA);
    store_set(stgA, 0);
    load_set(1, stgA);   // A holds g1 (stored at iter 0)
    load_set(2, stgB);   // B holds g2 (stored at iter 1)
    __syncthreads();     // buf0 ready

    for (int g = 0; g < NG; ++g) {
        // ---- LDS reads for group g ----
        const uint* tp = &lds[g & 1][r * LDSS + wb + 3];
        uint rv[3][6];
#pragma unroll
        for (int i = 0; i < 3; ++i)
#pragma unroll
            for (int j = 0; j < 6; ++j)
                rv[i][j] = tp[i * LDSS + j];

        // ---- packed weights (uniform s_loads; hoisted before vmcnt wait) ----
        uint w2[4][9];
        uint a2[4];
#pragma unroll
        for (int k = 0; k < 4; ++k) {
            const uint* wq = wsu + k * 288 + g * 9;
#pragma unroll
            for (int t = 0; t < 9; ++t) w2[k][t] = wq[t];
            a2[k] = wsu[APK_OFF + k * 32 + g];
        }

        // ---- store set (holds g+1, loaded 2 iters ago); refill with g+3 ----
        if (g + 1 < NG) {
            Unit* setp = (g & 1) ? stgB : stgA;
            store_set(setp, (g + 1) & 1);
            if (g + 3 < NG) load_set(g + 3, setp);
        }

        // ---- compute both channels of the pair via dot2 ----
#pragma unroll
        for (int k = 0; k < 4; ++k) {
#pragma unroll
            for (int p = 0; p < 4; ++p) {
                float acc = conv[k][p];
                acc = dot2(rv[0][p],     w2[k][0], acc);
                acc = dot2(rv[0][p + 1], w2[k][1], acc);
                acc = dot2(rv[0][p + 2], w2[k][2], acc);
                acc = dot2(rv[1][p],     w2[k][3], acc);
                acc = dot2(rv[1][p + 1], w2[k][4], acc);
                acc = dot2(rv[1][p + 2], w2[k][5], acc);
                acc = dot2(rv[2][p],     w2[k][6], acc);
                acc = dot2(rv[2][p + 1], w2[k][7], acc);
                acc = dot2(rv[2][p + 2], w2[k][8], acc);
                conv[k][p] = acc;
                logit[k][p] = dot2(rv[1][p + 1], a2[k], logit[k][p]);
            }
        }
        // one barrier per group: buf[g&1] reads done before iter g+1 rewrites
        // it; buf[(g+1)&1] writes visible for iter g+1's compute
        __syncthreads();
    }

    // ---- epilogue: softmax over K=4 + mixture (all f32) ----
    const float b0 = attn_b[0], b1 = attn_b[1], b2 = attn_b[2], b3 = attn_b[3];
    float4 o;
    float* op = &o.x;
#pragma unroll
    for (int p = 0; p < 4; ++p) {
        float l0 = logit[0][p] + b0;
        float l1 = logit[1][p] + b1;
        float l2 = logit[2][p] + b2;
        float l3 = logit[3][p] + b3;
        float m = fmaxf(fmaxf(l0, l1), fmaxf(l2, l3));
        float e0 = __expf(l0 - m), e1 = __expf(l1 - m);
        float e2 = __expf(l2 - m), e3 = __expf(l3 - m);
        float s = e0 + e1 + e2 + e3;
        float num = conv[0][p] * e0 + conv[1][p] * e1
                  + conv[2][p] * e2 + conv[3][p] * e3;
        op[p] = num / s;
    }
    size_t oidx = (size_t)b * PLANE + (size_t)(h0 + r) * WW + (w0 + wb);
    *reinterpret_cast<float4*>(out + oidx) = o;
}

extern "C" void kernel_launch(void* const* d_in, const int* in_sizes, int n_in,
                              void* d_out, int out_size, void* d_ws, size_t ws_size,
                              hipStream_t stream) {
    const float* x      = (const float*)d_in[0];
    const float* weight = (const float*)d_in[1];
    const float* attn_w = (const float*)d_in[2];
    const float* attn_b = (const float*)d_in[3];
    float* out = (float*)d_out;
    uint*  wsu = (uint*)d_ws;

    kwdc_pack<<<dim3(5), 256, 0, stream>>>(weight, attn_w, wsu);
    kwdc_main<<<dim3(512), NT, 0, stream>>>(x, wsu, attn_b, out);
}

// Round 15
// 81.924 us; speedup vs baseline: 1.1377x; 1.0323x over previous
//
#include <hip/hip_runtime.h>

// Fused KernelWarehouse dynamic conv, round 12 (base: R10, 82.2us):
//   logits = 1x1 conv -> softmax K=4 -> 3x3 convs -> mixture (dot2 f16 path).
// R11-R14 falsified barrier-semantics / barrier-count / LDS-width / fetch-
// volume theories (all null-to-negative). SIMDs idle ~64% with every pipe's
// demand << wall time -> suspect fixed PER-ITERATION latency tax (barrier
// spread + first-ds_read ~120cyc + vmcnt check + s_load latency).
// R15 test: halve iterations, double per-iter work. CPB=4 channels (2 dot2
// pairs) per group -> NG=16 iterations/barriers. Same total compute, fetch,
// and LDS traffic; 2x11.2=22.3 KB LDS (R2-proven); 4 blocks/CU unchanged.
// Everything else R10-verbatim.

typedef _Float16 half2_t __attribute__((ext_vector_type(2)));
typedef unsigned int uint;

#define HH 256
#define WW 256
#define CH 64
#define PLANE (HH * WW)
#define TILE 32
#define PAIRS 2                  // channel pairs per group
#define NG 16                    // groups (4 channels each)
#define ROWS 34                  // tile rows incl. halo
#define NC4 10                   // 4-dword units per row ([w0-4, w0+36))
#define LDSS 41                  // dword row stride (odd -> <=2-way read banks)
#define PSTRIDE (ROWS * LDSS)    // 1394 dwords per pair-plane
#define BUF_DW (PAIRS * PSTRIDE) // 2788 dwords per buffer (11.2 KB)
#define TU (PAIRS * ROWS * NC4)  // 680 units per group (unit = 4 px x 2 ch)
#define NS 3                     // units per thread (ceil 680/256)

// packed-weight table in d_ws:
//   uint wpk[4][32][9] : half2(w[k][2p][tap], w[k][2p+1][tap])  (1152)
//   uint apk[4][32]    : half2(attn_w[k][2p], attn_w[k][2p+1])  (128)
#define WPK_N 1152
#define APK_OFF 1152

__device__ __forceinline__ uint pkrtz(float a, float b) {
    return __builtin_bit_cast(uint, __builtin_amdgcn_cvt_pkrtz(a, b));
}

__device__ __forceinline__ float dot2(uint a, uint b, float c) {
#if __has_builtin(__builtin_amdgcn_fdot2)
    return __builtin_amdgcn_fdot2(__builtin_bit_cast(half2_t, a),
                                  __builtin_bit_cast(half2_t, b), c, false);
#else
    half2_t ha = __builtin_bit_cast(half2_t, a);
    half2_t hb = __builtin_bit_cast(half2_t, b);
    return c + (float)ha[0] * (float)hb[0] + (float)ha[1] * (float)hb[1];
#endif
}

__global__ void kwdc_pack(const float* __restrict__ weight,
                          const float* __restrict__ attn_w,
                          uint* __restrict__ wsu) {
    int e = blockIdx.x * 256 + threadIdx.x;
    if (e < WPK_N) {
        int k = e / 288, rem = e % 288, pair = rem / 9, tap = rem % 9;
        int c0 = 2 * pair;
        wsu[e] = pkrtz(weight[(k * CH + c0) * 9 + tap],
                       weight[(k * CH + c0 + 1) * 9 + tap]);
    } else if (e < WPK_N + 128) {
        int e2 = e - WPK_N;
        int k = e2 / 32, pair = e2 % 32;
        int c0 = 2 * pair;
        wsu[APK_OFF + e2] = pkrtz(attn_w[k * CH + c0], attn_w[k * CH + c0 + 1]);
    }
}

__global__ __launch_bounds__(256, 4) void kwdc_main(
    const float* __restrict__ x,       // [B,C,H,W] f32
    const uint*  __restrict__ wsu,     // packed weights (d_ws)
    const float* __restrict__ attn_b,  // [K] f32
    float* __restrict__ out)           // [B,1,H,W] f32
{
    __shared__ uint lds[2][BUF_DW];    // 2 x 11.2 KB

    const int tid = threadIdx.x;

    // XCD-aware decode: the 8 tiles of an image row share fid mod 8 -> same XCD
    const int fid = blockIdx.x;        // 0..1023
    const int tw = (fid >> 3) & 7;
    const int th = fid & 7;
    const int b  = fid >> 6;

    const int r  = tid >> 3;     // 0..31 row in tile
    const int cg = tid & 7;      // col group
    const int wb = cg * 4;       // col base (4-wide strip)

    const int h0 = th * TILE;
    const int w0 = tw * TILE;

    const float* xb = x + (size_t)b * CH * PLANE;

    // ---- staging metadata (unit = 4 px of one channel pair) ----
    int  s_ch[NS];      // pair within group (0/1)
    int  s_gofs[NS];
    int  s_lofs[NS];
    bool s_val[NS];
    bool s_act[NS];
#pragma unroll
    for (int s = 0; s < NS; ++s) {
        int i = tid + s * 256;
        bool act = i < TU;
        int col4  = i % NC4;
        int rowch = i / NC4;
        int row   = rowch % ROWS;
        int pr    = rowch / ROWS;         // pair 0/1
        int gh  = h0 + row - 1;
        int gw0 = w0 - 4 + col4 * 4;      // 16B-aligned; fully in or fully out
        s_act[s]  = act;
        s_val[s]  = act && ((unsigned)gh < HH) && ((unsigned)gw0 < WW);
        s_gofs[s] = gh * WW + gw0;
        s_lofs[s] = pr * PSTRIDE + row * LDSS + col4 * 4;
        s_ch[s]   = pr;
    }

    struct Unit { float4 a, b; };
    Unit stgA[NS], stgB[NS];           // 2-deep prefetch sets

    auto load_set = [&](int g, Unit* stg) {
#pragma unroll
        for (int s = 0; s < NS; ++s) {
            float4 va = {0.f, 0.f, 0.f, 0.f}, vb = va;
            if (s_val[s]) {
                const float* pa = xb + (size_t)(g * 4 + s_ch[s] * 2) * PLANE + s_gofs[s];
                va = *reinterpret_cast<const float4*>(pa);
                vb = *reinterpret_cast<const float4*>(pa + PLANE);
            }
            stg[s].a = va; stg[s].b = vb;
        }
    };

    auto store_set = [&](const Unit* stg, int buf) {
#pragma unroll
        for (int s = 0; s < NS; ++s) {
            if (s_act[s]) {
                uint* q = &lds[buf][s_lofs[s]];
                q[0] = pkrtz(stg[s].a.x, stg[s].b.x);
                q[1] = pkrtz(stg[s].a.y, stg[s].b.y);
                q[2] = pkrtz(stg[s].a.z, stg[s].b.z);
                q[3] = pkrtz(stg[s].a.w, stg[s].b.w);
            }
        }
    };

    float conv[4][4];
    float logit[4][4];
#pragma unroll
    for (int k = 0; k < 4; ++k)
#pragma unroll
        for (int p = 0; p < 4; ++p) { conv[k][p] = 0.f; logit[k][p] = 0.f; }

    // ---- prologue: stage group 0; prime 2-deep pipeline ----
    load_set(0, stgA);
    store_set(stgA, 0);
    load_set(1, stgA);   // A holds g1 (stored at iter 0)
    load_set(2, stgB);   // B holds g2 (stored at iter 1)
    __syncthreads();     // buf0 ready

    for (int g = 0; g < NG; ++g) {
        // ---- store set (holds g+1, loaded 2 iters ago); refill with g+3 ----
        if (g + 1 < NG) {
            Unit* setp = (g & 1) ? stgB : stgA;
            store_set(setp, (g + 1) & 1);
            if (g + 3 < NG) load_set(g + 3, setp);
        }

        // ---- compute the 2 pairs (4 channels) of this group ----
#pragma unroll
        for (int pr = 0; pr < PAIRS; ++pr) {
            const int gp = g * PAIRS + pr;       // global pair index 0..31
            const uint* tp = &lds[g & 1][pr * PSTRIDE + r * LDSS + wb + 3];
            uint rv[3][6];
#pragma unroll
            for (int i = 0; i < 3; ++i)
#pragma unroll
                for (int j = 0; j < 6; ++j)
                    rv[i][j] = tp[i * LDSS + j];

#pragma unroll
            for (int k = 0; k < 4; ++k) {
                const uint* wq = wsu + k * 288 + gp * 9;   // uniform -> s_load
                uint w2[9];
#pragma unroll
                for (int t = 0; t < 9; ++t) w2[t] = wq[t];
                const uint a2 = wsu[APK_OFF + k * 32 + gp];
#pragma unroll
                for (int p = 0; p < 4; ++p) {
                    float acc = conv[k][p];
                    acc = dot2(rv[0][p],     w2[0], acc);
                    acc = dot2(rv[0][p + 1], w2[1], acc);
                    acc = dot2(rv[0][p + 2], w2[2], acc);
                    acc = dot2(rv[1][p],     w2[3], acc);
                    acc = dot2(rv[1][p + 1], w2[4], acc);
                    acc = dot2(rv[1][p + 2], w2[5], acc);
                    acc = dot2(rv[2][p],     w2[6], acc);
                    acc = dot2(rv[2][p + 1], w2[7], acc);
                    acc = dot2(rv[2][p + 2], w2[8], acc);
                    conv[k][p] = acc;
                    logit[k][p] = dot2(rv[1][p + 1], a2, logit[k][p]);
                }
            }
        }
        // one barrier per group (16 total): buf[g&1] reads done before iter
        // g+1 rewrites it; buf[(g+1)&1] writes visible next iter
        __syncthreads();
    }

    // ---- epilogue: softmax over K=4 + mixture (all f32) ----
    const float b0 = attn_b[0], b1 = attn_b[1], b2 = attn_b[2], b3 = attn_b[3];
    float4 o;
    float* op = &o.x;
#pragma unroll
    for (int p = 0; p < 4; ++p) {
        float l0 = logit[0][p] + b0;
        float l1 = logit[1][p] + b1;
        float l2 = logit[2][p] + b2;
        float l3 = logit[3][p] + b3;
        float m = fmaxf(fmaxf(l0, l1), fmaxf(l2, l3));
        float e0 = __expf(l0 - m), e1 = __expf(l1 - m);
        float e2 = __expf(l2 - m), e3 = __expf(l3 - m);
        float s = e0 + e1 + e2 + e3;
        float num = conv[0][p] * e0 + conv[1][p] * e1
                  + conv[2][p] * e2 + conv[3][p] * e3;
        op[p] = num / s;
    }
    size_t oidx = (size_t)b * PLANE + (size_t)(h0 + r) * WW + (w0 + wb);
    *reinterpret_cast<float4*>(out + oidx) = o;
}

extern "C" void kernel_launch(void* const* d_in, const int* in_sizes, int n_in,
                              void* d_out, int out_size, void* d_ws, size_t ws_size,
                              hipStream_t stream) {
    const float* x      = (const float*)d_in[0];
    const float* weight = (const float*)d_in[1];
    const float* attn_w = (const float*)d_in[2];
    const float* attn_b = (const float*)d_in[3];
    float* out = (float*)d_out;
    uint*  wsu = (uint*)d_ws;

    kwdc_pack<<<dim3(5), 256, 0, stream>>>(weight, attn_w, wsu);
    kwdc_main<<<dim3(1024), 256, 0, stream>>>(x, wsu, attn_b, out);
}